// Round 5
// baseline (128.901 us; speedup 1.0000x reference)
//
#include <hip/hip_runtime.h>
#include <hip/hip_bf16.h>
#include <math.h>

// Stickbreaking attention, bf16 MFMA, flash-style suffix-scan carry.
// B=2 H=16 S=1024 D=64.
// Round-5 structure:
//   * prep kernel: K -> (Khi,Klo) split-bf16 and V -> V^T bf16, written once to d_ws
//     as padded (PITCH=72) tiles. Removes the per-iteration fp32->bf16 conversion
//     (was ~100 VALU/thread/iter, recomputed 16x per K-tile) from the main loop.
//   * main kernel: staging is a pure float4 copy (lane-consecutive, conflict-free),
//     double-buffered K/V LDS -> ONE barrier per iteration (was 3):
//       - Ws barrier removed: GEMM2's A-frag rows (16wv+l16) are written by the
//         same wave in the scan -> wave-local, intra-wave lgkmcnt ordering suffices.
//       - loop-end barrier removed via double buffer (write buf[p^1] while reading buf[p]).
//   * GEMM1 computes S^T (operand swap) so the suffix scan is in-register + 12 shuffles;
//     sigmoid fused into the exponent; causal mask = -1e30 sentinel.
// GEMM1 split-precision bf16 (3 MFMAs -> fp32-accurate logits); GEMM2 plain bf16.
// mfma_f32_16x16x32_bf16 layouts per m89/m120: A[m=lane&15][k=(lane>>4)*8+e],
// B[k][n=lane&15], C/D col=lane&15, row=(lane>>4)*4+reg.
// LDS: 2*3 tiles + Ws = 7 * 9216 B = 63 KB (<= 64 KB static limit), 2 blocks/CU.

typedef __attribute__((ext_vector_type(8))) short short8;
typedef __attribute__((ext_vector_type(4))) short short4v;
typedef __attribute__((ext_vector_type(4))) float f32x4;

#define PITCH 72          // bf16 elems per row (144 B): b128 frag reads 8/bank uniform
#define TILE_SH 4608      // shorts per 64x72 tile (9216 B)
#define BLOB_SH 13824     // shorts per (Kh,Kl,Vt) blob (27648 B = 1728 x 16B chunks)

__device__ inline short bf16r(float x) {
    __hip_bfloat16 h = __float2bfloat16(x);   // RNE
    return *(short*)&h;
}
__device__ inline float bf16f(short s) {
    union { unsigned u; float f; } c;
    c.u = ((unsigned)(unsigned short)s) << 16;
    return c.f;
}

// ---------------- prep: K -> hi/lo bf16, V -> V^T bf16, padded tiles in ws ----------------
__global__ __launch_bounds__(256) void stickbreak_prep(
    const float* __restrict__ Kg, const float* __restrict__ Vg,
    short* __restrict__ ws)
{
    const int t = threadIdx.x;
    const int n = blockIdx.x;                 // n = bh*16 + kt  (both strides collapse to n*4096)
    const float* kp = Kg + (size_t)n * 4096;
    const float* vp = Vg + (size_t)n * 4096;
    short* blob = ws + (size_t)n * BLOB_SH;

    // K: 16 floats/thread -> hi/lo short8 pairs
    {
        const int srow = t >> 2;
        const int scol = (t & 3) << 4;
        const float* src = kp + srow * 64 + scol;
        short8 h0, h1, l0, l1;
        #pragma unroll
        for (int i = 0; i < 16; i += 4) {
            const float4 f = *(const float4*)(src + i);
            float a[4] = {f.x, f.y, f.z, f.w};
            #pragma unroll
            for (int j = 0; j < 4; ++j) {
                const short hi = bf16r(a[j]);
                const short lo = bf16r(a[j] - bf16f(hi));
                const int idx = i + j;
                if (idx < 8) { h0[idx] = hi; l0[idx] = lo; }
                else         { h1[idx - 8] = hi; l1[idx - 8] = lo; }
            }
        }
        *(short8*)&blob[srow * PITCH + scol]               = h0;
        *(short8*)&blob[srow * PITCH + scol + 8]           = h1;
        *(short8*)&blob[TILE_SH + srow * PITCH + scol]     = l0;
        *(short8*)&blob[TILE_SH + srow * PITCH + scol + 8] = l1;
    }
    // V: 4x4 register-block transpose -> Vt[d][j] bf16
    {
        const int vj = (t & 15) << 2;
        const int vd = (t >> 4) << 2;
        float rr[4][4];
        #pragma unroll
        for (int r = 0; r < 4; ++r) {
            const float4 f = *(const float4*)(vp + (vj + r) * 64 + vd);
            rr[r][0] = f.x; rr[r][1] = f.y; rr[r][2] = f.z; rr[r][3] = f.w;
        }
        #pragma unroll
        for (int x = 0; x < 4; ++x) {
            short4v w4;
            #pragma unroll
            for (int r = 0; r < 4; ++r) w4[r] = bf16r(rr[r][x]);
            *(short4v*)&blob[2 * TILE_SH + (vd + x) * PITCH + vj] = w4;
        }
    }
}

// ---------------- main ----------------
__global__ __launch_bounds__(256, 2) void stickbreak_main(
    const float* __restrict__ Qg, const short* __restrict__ ws,
    float* __restrict__ Og)
{
    __shared__ __align__(16) short buf[2][3 * TILE_SH];   // [Kh][Kl][Vt], double-buffered
    __shared__ __align__(16) short Ws[TILE_SH];           // W strip [i][j] (wave-local rows)

    const int t = threadIdx.x;
    const int n = blockIdx.x;                 // 0..511
    // n&7 fastest -> all 16 q-tiles of one head share an XCD slot (blob L2 reuse).
    const int bh = (n & 7) + 8 * (n >> 7);    // 0..31
    const int qr = (n >> 3) & 15;
    const int qt = (n >> 8) ? (15 - qr) : qr; // complementary length pairing c <-> c+256

    const size_t hbase = (size_t)bh * 1024 * 64;
    const float* qp = Qg + hbase + (size_t)qt * 64 * 64;
    const short* wsbase = ws + (size_t)bh * 16 * BLOB_SH;
    float*       op = Og + hbase + (size_t)qt * 64 * 64;

    const int lane = t & 63;
    const int wv   = t >> 6;      // wave 0..3 -> q-rows [16wv, 16wv+16)
    const int l16  = lane & 15;
    const int q4   = lane >> 4;   // quad 0..3

    // ---- Q fragments straight to registers (loop-invariant, hi/lo split) ----
    short8 qfh[2], qfl[2];
    {
        const float* qrow = qp + (16 * wv + l16) * 64;
        #pragma unroll
        for (int ks = 0; ks < 2; ++ks) {
            const int base = 32 * ks + 8 * q4;
            const float4 f0 = *(const float4*)(qrow + base);
            const float4 f1 = *(const float4*)(qrow + base + 4);
            float a[8] = {f0.x, f0.y, f0.z, f0.w, f1.x, f1.y, f1.z, f1.w};
            #pragma unroll
            for (int j = 0; j < 8; ++j) {
                const short hi = bf16r(a[j]);
                qfh[ks][j] = hi;
                qfl[ks][j] = bf16r(a[j] - bf16f(hi));
            }
        }
    }

    f32x4 Oacc[4];
    #pragma unroll
    for (int i = 0; i < 4; ++i) Oacc[i] = (f32x4){0.f, 0.f, 0.f, 0.f};
    float Crow = 0.f;    // carried suffix sum for q-row 16wv+l16 (replicated over q4)

    // ---- prologue: stage tile qt into buf[0] (pure float4 copy, 1728 chunks) ----
    {
        const float4* g = (const float4*)(wsbase + (size_t)qt * BLOB_SH);
        float4* b = (float4*)buf[0];
        #pragma unroll
        for (int c = 0; c < 6; ++c) b[t + 256 * c] = g[t + 256 * c];
        if (t < 192) b[t + 1536] = g[t + 1536];
    }

    int p = 0;
    float4 pf[7];
    for (int kt = qt; kt >= 0; --kt) {
        __syncthreads();   // buf[p] staged & visible; prior reads of buf[p^1] complete

        // ---- issue next-tile global loads early (latency hidden behind GEMM1/scan) ----
        if (kt > 0) {
            const float4* g = (const float4*)(wsbase + (size_t)(kt - 1) * BLOB_SH);
            #pragma unroll
            for (int c = 0; c < 6; ++c) pf[c] = g[t + 256 * c];
            if (t < 192) pf[6] = g[t + 1536];
        }

        const short* Kh = &buf[p][0];
        const short* Kl = &buf[p][TILE_SH];
        const short* Vt = &buf[p][2 * TILE_SH];

        // ---- GEMM1: S^T = K Q^T (split precision, 3 MFMAs per frag pair) ----
        // D[m=j][n=i]: col i = l16, row j = 16nt + 4q4 + reg.
        f32x4 Sacc[4];
        #pragma unroll
        for (int i = 0; i < 4; ++i) Sacc[i] = (f32x4){0.f, 0.f, 0.f, 0.f};
        #pragma unroll
        for (int ks = 0; ks < 2; ++ks) {
            #pragma unroll
            for (int nt = 0; nt < 4; ++nt) {
                const short8 ah = *(const short8*)&Kh[(16 * nt + l16) * PITCH + 32 * ks + 8 * q4];
                const short8 al = *(const short8*)&Kl[(16 * nt + l16) * PITCH + 32 * ks + 8 * q4];
                Sacc[nt] = __builtin_amdgcn_mfma_f32_16x16x32_bf16(ah, qfh[ks], Sacc[nt], 0, 0, 0);
                Sacc[nt] = __builtin_amdgcn_mfma_f32_16x16x32_bf16(al, qfh[ks], Sacc[nt], 0, 0, 0);
                Sacc[nt] = __builtin_amdgcn_mfma_f32_16x16x32_bf16(ah, qfl[ks], Sacc[nt], 0, 0, 0);
            }
        }

        // ---- elementwise + suffix scan (lane owns q-row i=16wv+l16; j = 16nt+4q4+reg) ----
        const bool diag = (kt == qt);
        const int irow = 16 * wv + l16;
        float ex[4][4];                          // l + lb + in-run inclusive suffix
        float sR[4];                             // 4-run totals
        #pragma unroll
        for (int nt = 0; nt < 4; ++nt) {
            float lbr[4], lv[4];
            #pragma unroll
            for (int reg = 0; reg < 4; ++reg) {
                float l = Sacc[nt][reg] * 0.125f;
                if (diag && (16 * nt + 4 * q4 + reg > irow)) l = -1e30f;  // mask sentinel
                const float e  = __expf(-fabsf(l));
                const float lb = -(fmaxf(l, 0.f) + __logf(1.f + e));     // -softplus(l)
                lv[reg] = l; lbr[reg] = lb;
            }
            const float s3 = lbr[3];
            const float s2 = lbr[2] + s3;
            const float s1 = lbr[1] + s2;
            const float s0 = lbr[0] + s1;
            ex[nt][0] = lv[0] + lbr[0] + s0;
            ex[nt][1] = lv[1] + lbr[1] + s1;
            ex[nt][2] = lv[2] + lbr[2] + s2;
            ex[nt][3] = lv[3] + lbr[3] + s3;
            sR[nt] = s0;
        }
        float gq[4], Tn[4];
        #pragma unroll
        for (int nt = 0; nt < 4; ++nt) {
            float g = sR[nt];
            float u = __shfl_down(g, 16, 64); if (q4 < 3) g += u;
            u = __shfl_down(g, 32, 64);       if (q4 < 2) g += u;
            gq[nt] = g;                          // sum over q4' >= q4 within nt
            Tn[nt] = __shfl(g, l16, 64);         // nt total (q4=0 lane, same i)
        }
        const float TSa[4] = { Tn[1] + Tn[2] + Tn[3], Tn[2] + Tn[3], Tn[3], 0.f };
        #pragma unroll
        for (int nt = 0; nt < 4; ++nt) {
            const float cross = (gq[nt] - sR[nt]) + TSa[nt] + Crow;
            short4v w4;
            #pragma unroll
            for (int reg = 0; reg < 4; ++reg)
                w4[reg] = bf16r(__expf(ex[nt][reg] + cross));
            *(short4v*)&Ws[irow * PITCH + 16 * nt + 4 * q4] = w4;   // wave-local rows
        }
        Crow += TSa[0] + Tn[0];

        // ---- stage next tile into buf[p^1] (no barrier needed: disjoint buffer) ----
        if (kt > 0) {
            float4* b = (float4*)buf[p ^ 1];
            #pragma unroll
            for (int c = 0; c < 6; ++c) b[t + 256 * c] = pf[c];
            if (t < 192) b[t + 1536] = pf[6];
        }

        // ---- GEMM2: O += W V  (Ws rows are wave-local; Vt from buf[p]) ----
        #pragma unroll
        for (int ks = 0; ks < 2; ++ks) {
            const short8 wa = *(const short8*)&Ws[(16 * wv + l16) * PITCH + 32 * ks + 8 * q4];
            #pragma unroll
            for (int dt = 0; dt < 4; ++dt) {
                const short8 vb = *(const short8*)&Vt[(16 * dt + l16) * PITCH + 32 * ks + 8 * q4];
                Oacc[dt] = __builtin_amdgcn_mfma_f32_16x16x32_bf16(wa, vb, Oacc[dt], 0, 0, 0);
            }
        }

        p ^= 1;
    }

    // ---- epilogue: C-layout scatter to global (fp32) ----
    #pragma unroll
    for (int dt = 0; dt < 4; ++dt)
        #pragma unroll
        for (int r = 0; r < 4; ++r)
            op[(16 * wv + 4 * q4 + r) * 64 + 16 * dt + l16] = Oacc[dt][r];
}

extern "C" void kernel_launch(void* const* d_in, const int* in_sizes, int n_in,
                              void* d_out, int out_size, void* d_ws, size_t ws_size,
                              hipStream_t stream) {
    const float* q = (const float*)d_in[0];
    const float* k = (const float*)d_in[1];
    const float* v = (const float*)d_in[2];
    float* out = (float*)d_out;
    short* ws = (short*)d_ws;
    stickbreak_prep<<<dim3(512), dim3(256), 0, stream>>>(k, v, ws);
    stickbreak_main<<<dim3(512), dim3(256), 0, stream>>>(q, ws, out);
}

// Round 6
// 109.547 us; speedup vs baseline: 1.1767x; 1.1767x over previous
//
#include <hip/hip_runtime.h>
#include <hip/hip_bf16.h>
#include <math.h>

// Stickbreaking attention, bf16 MFMA, flash-style suffix-scan carry.
// B=2 H=16 S=1024 D=64.
// Round-6 structure: BARRIER-FREE main loop.
//   * prep kernel writes K->(hi,lo) and V->V^T bf16 into d_ws in EXACT MFMA
//     fragment order: sub-block s = nt*2+ks holds 64 lanes x 16 B, lane's 16 B
//     IS its A/B fragment. Main reads fragments with coalesced
//     global_load_dwordx4 (1 KB/wave/instr) straight from L1/L2 - no LDS
//     staging, no __syncthreads at all. A 24.6 KB blob fits 32 KB L1; the 4
//     waves of a block (and the 16 q-blocks of a head, XCD-swizzled) share it.
//   * only LDS: the 9 KB wave-local Ws round-trip (C-layout -> A-layout for
//     GEMM2); waves write disjoint rows, intra-wave lgkmcnt ordering suffices.
//   * per iteration: issue all 24 frag loads (kh/kl first; vb stays in flight
//     through the scan) -> one exposed L2 latency + ~1.5K cyc compute; waves
//     on one SIMD overlap across different iterations freely (no sync points).
//   * GEMM1 computes S^T (operand swap) so the suffix scan is in-register +
//     12 shuffles; sigmoid fused into exponent; causal mask = -1e30 sentinel.
// GEMM1 split-precision bf16 (3 MFMAs -> fp32-accurate logits); GEMM2 plain
// bf16. mfma_f32_16x16x32_bf16 layouts per m89/m120: A[m=lane&15][k=q4*8+e],
// B[k][n=lane&15], C/D col=lane&15, row=q4*4+reg.

typedef __attribute__((ext_vector_type(8))) short short8;
typedef __attribute__((ext_vector_type(4))) short short4v;
typedef __attribute__((ext_vector_type(4))) float f32x4;

#define WPITCH 72        // Ws row pitch (shorts): b64 writes / b128 reads bank-uniform
#define BLOB_SH 12288    // shorts per tile blob: Kh 4096 | Kl 4096 | Vt 4096 (24576 B)

__device__ inline short bf16r(float x) {
    __hip_bfloat16 h = __float2bfloat16(x);   // RNE
    return *(short*)&h;
}
__device__ inline float bf16f(short s) {
    union { unsigned u; float f; } c;
    c.u = ((unsigned)(unsigned short)s) << 16;
    return c.f;
}

// ---------------- prep: frag-order blobs in ws ----------------
// blob[s*512 + lane*8 + e]          = bf16_hi( K[16*nt+l16][32*ks+8*q4+e] )
// blob[4096 + s*512 + lane*8 + e]   = bf16_lo( same )
// blob[8192 + s*512 + lane*8 + e]   = bf16( V[32*ks+8*q4+e][16*dt+l16] )   (V^T)
// with s = nt*2+ks (= dt*2+ks), lane = l16 + 16*q4.
__global__ __launch_bounds__(256) void stickbreak_prep(
    const float* __restrict__ Kg, const float* __restrict__ Vg,
    short* __restrict__ ws)
{
    const int t = threadIdx.x;
    const int n = blockIdx.x;                 // n = bh*16 + kt (strides collapse)
    const float* kp = Kg + (size_t)n * 4096;
    const float* vp = Vg + (size_t)n * 4096;
    short* blob = ws + (size_t)n * BLOB_SH;

    const int lane = t & 63;
    const int l16 = lane & 15;
    const int q4 = lane >> 4;
    const int s0 = t >> 6;                    // 0..3

    #pragma unroll
    for (int w = 0; w < 2; ++w) {
        const int s  = s0 + 4 * w;            // 0..7
        const int nt = s >> 1;
        const int ks = s & 1;
        // K hi/lo fragment
        {
            const float* src = kp + (16 * nt + l16) * 64 + 32 * ks + 8 * q4;
            const float4 f0 = *(const float4*)src;
            const float4 f1 = *(const float4*)(src + 4);
            float a[8] = {f0.x, f0.y, f0.z, f0.w, f1.x, f1.y, f1.z, f1.w};
            short8 h, l;
            #pragma unroll
            for (int e = 0; e < 8; ++e) {
                h[e] = bf16r(a[e]);
                l[e] = bf16r(a[e] - bf16f(h[e]));
            }
            *(short8*)&blob[s * 512 + lane * 8]        = h;
            *(short8*)&blob[4096 + s * 512 + lane * 8] = l;
        }
        // V^T fragment (gather: 8 strided scalar loads)
        {
            const float* vsrc = vp + (32 * ks + 8 * q4) * 64 + 16 * nt + l16;
            short8 wv8;
            #pragma unroll
            for (int e = 0; e < 8; ++e) wv8[e] = bf16r(vsrc[e * 64]);
            *(short8*)&blob[8192 + s * 512 + lane * 8] = wv8;
        }
    }
}

// ---------------- main (barrier-free) ----------------
__global__ __launch_bounds__(256, 2) void stickbreak_main(
    const float* __restrict__ Qg, const short* __restrict__ ws,
    float* __restrict__ Og)
{
    __shared__ __align__(16) short Ws[64 * WPITCH];   // 9216 B, wave-local rows

    const int t = threadIdx.x;
    const int n = blockIdx.x;                 // 0..511
    // n&7 fastest -> all 16 q-tiles of one head share an XCD slot (blob L2 reuse).
    const int bh = (n & 7) + 8 * (n >> 7);    // 0..31
    const int qr = (n >> 3) & 15;
    const int qt = (n >> 8) ? (15 - qr) : qr; // complementary length pairing c <-> c+256

    const size_t hbase = (size_t)bh * 1024 * 64;
    const float* qp = Qg + hbase + (size_t)qt * 64 * 64;
    const short* blobs = ws + (size_t)bh * 16 * BLOB_SH;
    float*       op = Og + hbase + (size_t)qt * 64 * 64;

    const int lane = t & 63;
    const int wv   = t >> 6;      // wave 0..3 -> q-rows [16wv, 16wv+16)
    const int l16  = lane & 15;
    const int q4   = lane >> 4;   // quad 0..3

    // ---- Q fragments straight to registers (loop-invariant, hi/lo split) ----
    short8 qfh[2], qfl[2];
    {
        const float* qrow = qp + (16 * wv + l16) * 64;
        #pragma unroll
        for (int ks = 0; ks < 2; ++ks) {
            const int base = 32 * ks + 8 * q4;
            const float4 f0 = *(const float4*)(qrow + base);
            const float4 f1 = *(const float4*)(qrow + base + 4);
            float a[8] = {f0.x, f0.y, f0.z, f0.w, f1.x, f1.y, f1.z, f1.w};
            #pragma unroll
            for (int j = 0; j < 8; ++j) {
                const short hi = bf16r(a[j]);
                qfh[ks][j] = hi;
                qfl[ks][j] = bf16r(a[j] - bf16f(hi));
            }
        }
    }

    f32x4 Oacc[4];
    #pragma unroll
    for (int i = 0; i < 4; ++i) Oacc[i] = (f32x4){0.f, 0.f, 0.f, 0.f};
    float Crow = 0.f;    // carried suffix sum for q-row 16wv+l16 (replicated over q4)

    for (int kt = qt; kt >= 0; --kt) {
        const short* blob = blobs + (size_t)kt * BLOB_SH;

        // ---- issue all fragment loads: kh/kl first (GEMM1), vb stays in flight ----
        short8 kh[8], kl[8], vb[8];
        #pragma unroll
        for (int s = 0; s < 8; ++s) {
            kh[s] = *(const short8*)&blob[s * 512 + lane * 8];
            kl[s] = *(const short8*)&blob[4096 + s * 512 + lane * 8];
        }
        #pragma unroll
        for (int s = 0; s < 8; ++s)
            vb[s] = *(const short8*)&blob[8192 + s * 512 + lane * 8];

        // ---- GEMM1: S^T = K Q^T (split precision, 3 MFMAs per frag pair) ----
        // D[m=j][n=i]: col i = l16, row j = 16nt + 4q4 + reg.
        f32x4 Sacc[4];
        #pragma unroll
        for (int i = 0; i < 4; ++i) Sacc[i] = (f32x4){0.f, 0.f, 0.f, 0.f};
        #pragma unroll
        for (int ks = 0; ks < 2; ++ks) {
            #pragma unroll
            for (int nt = 0; nt < 4; ++nt) {
                const int s = nt * 2 + ks;
                Sacc[nt] = __builtin_amdgcn_mfma_f32_16x16x32_bf16(kh[s], qfh[ks], Sacc[nt], 0, 0, 0);
                Sacc[nt] = __builtin_amdgcn_mfma_f32_16x16x32_bf16(kl[s], qfh[ks], Sacc[nt], 0, 0, 0);
                Sacc[nt] = __builtin_amdgcn_mfma_f32_16x16x32_bf16(kh[s], qfl[ks], Sacc[nt], 0, 0, 0);
            }
        }

        // ---- elementwise + suffix scan (lane owns q-row i=16wv+l16; j = 16nt+4q4+reg) ----
        const bool diag = (kt == qt);
        const int irow = 16 * wv + l16;
        float ex[4][4];                          // l + lb + in-run inclusive suffix
        float sR[4];                             // 4-run totals
        #pragma unroll
        for (int nt = 0; nt < 4; ++nt) {
            float lbr[4], lv[4];
            #pragma unroll
            for (int reg = 0; reg < 4; ++reg) {
                float l = Sacc[nt][reg] * 0.125f;
                if (diag && (16 * nt + 4 * q4 + reg > irow)) l = -1e30f;  // mask sentinel
                const float e  = __expf(-fabsf(l));
                const float lb = -(fmaxf(l, 0.f) + __logf(1.f + e));     // -softplus(l)
                lv[reg] = l; lbr[reg] = lb;
            }
            const float s3 = lbr[3];
            const float s2 = lbr[2] + s3;
            const float s1 = lbr[1] + s2;
            const float s0 = lbr[0] + s1;
            ex[nt][0] = lv[0] + lbr[0] + s0;
            ex[nt][1] = lv[1] + lbr[1] + s1;
            ex[nt][2] = lv[2] + lbr[2] + s2;
            ex[nt][3] = lv[3] + lbr[3] + s3;
            sR[nt] = s0;
        }
        float gq[4], Tn[4];
        #pragma unroll
        for (int nt = 0; nt < 4; ++nt) {
            float g = sR[nt];
            float u = __shfl_down(g, 16, 64); if (q4 < 3) g += u;
            u = __shfl_down(g, 32, 64);       if (q4 < 2) g += u;
            gq[nt] = g;                          // sum over q4' >= q4 within nt
            Tn[nt] = __shfl(g, l16, 64);         // nt total (q4=0 lane, same i)
        }
        const float TSa[4] = { Tn[1] + Tn[2] + Tn[3], Tn[2] + Tn[3], Tn[3], 0.f };
        #pragma unroll
        for (int nt = 0; nt < 4; ++nt) {
            const float cross = (gq[nt] - sR[nt]) + TSa[nt] + Crow;
            short4v w4;
            #pragma unroll
            for (int reg = 0; reg < 4; ++reg)
                w4[reg] = bf16r(__expf(ex[nt][reg] + cross));
            *(short4v*)&Ws[irow * WPITCH + 16 * nt + 4 * q4] = w4;   // wave-local rows
        }
        Crow += TSa[0] + Tn[0];

        // ---- GEMM2: O += W V  (wa via wave-local LDS round-trip; vb already in flight) ----
        #pragma unroll
        for (int ks = 0; ks < 2; ++ks) {
            const short8 wa = *(const short8*)&Ws[(16 * wv + l16) * WPITCH + 32 * ks + 8 * q4];
            #pragma unroll
            for (int dt = 0; dt < 4; ++dt) {
                Oacc[dt] = __builtin_amdgcn_mfma_f32_16x16x32_bf16(wa, vb[dt * 2 + ks], Oacc[dt], 0, 0, 0);
            }
        }
    }

    // ---- epilogue: C-layout scatter to global (fp32) ----
    #pragma unroll
    for (int dt = 0; dt < 4; ++dt)
        #pragma unroll
        for (int r = 0; r < 4; ++r)
            op[(16 * wv + 4 * q4 + r) * 64 + 16 * dt + l16] = Oacc[dt][r];
}

extern "C" void kernel_launch(void* const* d_in, const int* in_sizes, int n_in,
                              void* d_out, int out_size, void* d_ws, size_t ws_size,
                              hipStream_t stream) {
    const float* q = (const float*)d_in[0];
    const float* k = (const float*)d_in[1];
    const float* v = (const float*)d_in[2];
    float* out = (float*)d_out;
    short* ws = (short*)d_ws;
    stickbreak_prep<<<dim3(512), dim3(256), 0, stream>>>(k, v, ws);
    stickbreak_main<<<dim3(512), dim3(256), 0, stream>>>(q, ws, out);
}

// Round 7
// 107.603 us; speedup vs baseline: 1.1979x; 1.0181x over previous
//
#include <hip/hip_runtime.h>
#include <hip/hip_bf16.h>
#include <math.h>

// Stickbreaking attention, bf16 MFMA, flash-style suffix-scan carry.
// B=2 H=16 S=1024 D=64.
// Round-7: split-K 2-way on top of the round-6 barrier-free main loop.
//   * main grid 1024: q-tile qt -> hi block (tiles [nl..qt], nl=(qt+1)>>1, has the
//     diagonal) and lo block (tiles [0..nl)). O = O_hi + exp(C_hi)*O_lo, with
//     C_hi[i] = hi-range row total of log_beta (the Crow carry). 4 blocks/CU
//     (was 2) doubles latency hiding; dispatch rounds arranged so each CU's
//     4 blocks sum to 17 iterations: hi(x)+hi(15-x)+lo(x)+lo(15-x) = 17.
//   * merge kernel: out = O_hi + exp(C_hi)*O_lo (512 blocks, ~24 MB traffic).
//   * prep: V transposed through LDS (pitch 66, float2 staging) instead of the
//     stride-256B global gather; K hi/lo split unchanged. Frag-order blobs:
//     lane's 16 B IS its MFMA fragment; main reads them with coalesced
//     global_load_dwordx4 from L1/L2, no LDS staging, no __syncthreads.
//   * GEMM1 per-ks load batching + vb issued after GEMM1: peak live VGPR ~100,
//     fits __launch_bounds__(256,4).
// GEMM1 split-precision bf16 (3 MFMAs -> fp32-accurate logits); GEMM2 plain
// bf16. mfma_f32_16x16x32_bf16 layouts per m89/m120: A[m=lane&15][k=q4*8+e],
// B[k][n=lane&15], C/D col=lane&15, row=q4*4+reg.

typedef __attribute__((ext_vector_type(8))) short short8;
typedef __attribute__((ext_vector_type(4))) short short4v;
typedef __attribute__((ext_vector_type(4))) float f32x4;

#define WPITCH 72        // Ws row pitch (shorts): b64 writes / b128 reads bank-uniform
#define BLOB_SH 12288    // shorts per tile blob: Kh 4096 | Kl 4096 | Vt 4096 (24576 B)
#define NBLOB 512        // 32 heads x 16 tiles
#define VP 66            // prep V-transpose LDS pitch (floats): even (float2-align),
                         // 8*66 % 32 = 16 -> quads split banks, <=2-way on reads

__device__ inline short bf16r(float x) {
    __hip_bfloat16 h = __float2bfloat16(x);   // RNE
    return *(short*)&h;
}
__device__ inline float bf16f(short s) {
    union { unsigned u; float f; } c;
    c.u = ((unsigned)(unsigned short)s) << 16;
    return c.f;
}

// ---------------- prep: frag-order blobs in ws ----------------
// blob[s*512 + lane*8 + e]        = bf16_hi( K[16*nt+l16][32*ks+8*q4+e] )
// blob[4096 + s*512 + lane*8 + e] = bf16_lo( same )
// blob[8192 + s*512 + lane*8 + e] = bf16( V[32*ks+8*q4+e][16*nt+l16] )
// with s = nt*2+ks, lane = l16 + 16*q4.
__global__ __launch_bounds__(256) void stickbreak_prep(
    const float* __restrict__ Kg, const float* __restrict__ Vg,
    short* __restrict__ ws)
{
    __shared__ float Vlds[64 * VP];

    const int t = threadIdx.x;
    const int n = blockIdx.x;                 // n = bh*16 + kt (strides collapse)
    const float* kp = Kg + (size_t)n * 4096;
    const float* vp = Vg + (size_t)n * 4096;
    short* blob = ws + (size_t)n * BLOB_SH;

    const int lane = t & 63;
    const int l16 = lane & 15;
    const int q4 = lane >> 4;
    const int s0 = t >> 6;                    // 0..3

    // stage V into LDS (coalesced float4 global reads, float2 LDS writes)
    {
        const int row = t >> 2;
        const int cb = (t & 3) << 4;
        #pragma unroll
        for (int c = 0; c < 4; ++c) {
            const float4 f = *(const float4*)(vp + row * 64 + cb + 4 * c);
            *(float2*)&Vlds[row * VP + cb + 4 * c]     = make_float2(f.x, f.y);
            *(float2*)&Vlds[row * VP + cb + 4 * c + 2] = make_float2(f.z, f.w);
        }
    }

    // K hi/lo fragments (independent of LDS; overlaps the barrier)
    #pragma unroll
    for (int w = 0; w < 2; ++w) {
        const int s  = s0 + 4 * w;            // 0..7
        const int nt = s >> 1;
        const int ks = s & 1;
        const float* src = kp + (16 * nt + l16) * 64 + 32 * ks + 8 * q4;
        const float4 f0 = *(const float4*)src;
        const float4 f1 = *(const float4*)(src + 4);
        float a[8] = {f0.x, f0.y, f0.z, f0.w, f1.x, f1.y, f1.z, f1.w};
        short8 h, l;
        #pragma unroll
        for (int e = 0; e < 8; ++e) {
            h[e] = bf16r(a[e]);
            l[e] = bf16r(a[e] - bf16f(h[e]));
        }
        *(short8*)&blob[s * 512 + lane * 8]        = h;
        *(short8*)&blob[4096 + s * 512 + lane * 8] = l;
    }

    __syncthreads();

    // transposed V reads -> frag-order bf16 blob
    #pragma unroll
    for (int w = 0; w < 2; ++w) {
        const int s  = s0 + 4 * w;
        const int nt = s >> 1;
        const int ks = s & 1;
        const int d  = 16 * nt + l16;
        const int jb = 32 * ks + 8 * q4;
        short8 wv8;
        #pragma unroll
        for (int e = 0; e < 8; ++e) wv8[e] = bf16r(Vlds[(jb + e) * VP + d]);
        *(short8*)&blob[8192 + s * 512 + lane * 8] = wv8;
    }
}

// ---------------- main (barrier-free, split-K halves) ----------------
// part layout (floats): part[g*8192 + 0..4095] = O_hi, +4096..8191 = O_lo,
//                       part[NBLOB*8192 + g*64 + i] = C_hi row totals; g = bh*16+qt.
__global__ __launch_bounds__(256, 4) void stickbreak_main(
    const float* __restrict__ Qg, const short* __restrict__ ws,
    float* __restrict__ part)
{
    __shared__ __align__(16) short Ws[64 * WPITCH];   // 9216 B, wave-local rows

    const int t = threadIdx.x;
    const int n = blockIdx.x;                 // 0..1023
    const int half = n >> 9;                  // 0 = hi (diag side), 1 = lo
    const int m = n & 511;
    // m&7 fastest -> q-tiles/halves of one head share an XCD (blob L2 reuse).
    const int bh = (m & 7) + 8 * (m >> 7);    // 0..31
    const int qr = (m >> 3) & 15;
    const int qt = (m >> 8) ? (15 - qr) : qr; // complementary length pairing
    const int nl = (qt + 1) >> 1;             // lo tile count: tiles [0, nl)
    const int kstart = half ? (nl - 1) : qt;
    const int kend   = half ? 0 : nl;

    const size_t hbase = (size_t)bh * 1024 * 64;
    const float* qp = Qg + hbase + (size_t)qt * 64 * 64;
    const short* blobs = ws + (size_t)bh * 16 * BLOB_SH;
    const int g = bh * 16 + qt;
    float* opart = part + (size_t)g * 8192 + (half ? 4096 : 0);
    float* Cb = part + (size_t)NBLOB * 8192;

    const int lane = t & 63;
    const int wv   = t >> 6;      // wave 0..3 -> q-rows [16wv, 16wv+16)
    const int l16  = lane & 15;
    const int q4   = lane >> 4;   // quad 0..3

    // ---- Q fragments straight to registers (loop-invariant, hi/lo split) ----
    short8 qfh[2], qfl[2];
    {
        const float* qrow = qp + (16 * wv + l16) * 64;
        #pragma unroll
        for (int ks = 0; ks < 2; ++ks) {
            const int base = 32 * ks + 8 * q4;
            const float4 f0 = *(const float4*)(qrow + base);
            const float4 f1 = *(const float4*)(qrow + base + 4);
            float a[8] = {f0.x, f0.y, f0.z, f0.w, f1.x, f1.y, f1.z, f1.w};
            #pragma unroll
            for (int j = 0; j < 8; ++j) {
                const short hi = bf16r(a[j]);
                qfh[ks][j] = hi;
                qfl[ks][j] = bf16r(a[j] - bf16f(hi));
            }
        }
    }

    f32x4 Oacc[4];
    #pragma unroll
    for (int i = 0; i < 4; ++i) Oacc[i] = (f32x4){0.f, 0.f, 0.f, 0.f};
    float Crow = 0.f;    // carried suffix sum for q-row 16wv+l16 (replicated over q4)

    for (int kt = kstart; kt >= kend; --kt) {
        const short* blob = blobs + (size_t)kt * BLOB_SH;

        // ---- GEMM1: S^T = K Q^T (split precision), per-ks load batching ----
        // D[m=j][n=i]: col i = l16, row j = 16nt + 4q4 + reg.
        f32x4 Sacc[4];
        #pragma unroll
        for (int i = 0; i < 4; ++i) Sacc[i] = (f32x4){0.f, 0.f, 0.f, 0.f};
        #pragma unroll
        for (int ks = 0; ks < 2; ++ks) {
            short8 kh[4], kl[4];
            #pragma unroll
            for (int nt = 0; nt < 4; ++nt) {
                const int s = nt * 2 + ks;
                kh[nt] = *(const short8*)&blob[s * 512 + lane * 8];
                kl[nt] = *(const short8*)&blob[4096 + s * 512 + lane * 8];
            }
            #pragma unroll
            for (int nt = 0; nt < 4; ++nt) {
                Sacc[nt] = __builtin_amdgcn_mfma_f32_16x16x32_bf16(kh[nt], qfh[ks], Sacc[nt], 0, 0, 0);
                Sacc[nt] = __builtin_amdgcn_mfma_f32_16x16x32_bf16(kl[nt], qfh[ks], Sacc[nt], 0, 0, 0);
                Sacc[nt] = __builtin_amdgcn_mfma_f32_16x16x32_bf16(kh[nt], qfl[ks], Sacc[nt], 0, 0, 0);
            }
        }

        // ---- issue V fragment loads now; they stay in flight through the scan ----
        short8 vb[8];
        #pragma unroll
        for (int s = 0; s < 8; ++s)
            vb[s] = *(const short8*)&blob[8192 + s * 512 + lane * 8];

        // ---- elementwise + suffix scan (lane owns q-row i=16wv+l16; j = 16nt+4q4+reg) ----
        const bool diag = (half == 0) && (kt == qt);
        const int irow = 16 * wv + l16;
        float ex[4][4];                          // l + lb + in-run inclusive suffix
        float sR[4];                             // 4-run totals
        #pragma unroll
        for (int nt = 0; nt < 4; ++nt) {
            float lbr[4], lv[4];
            #pragma unroll
            for (int reg = 0; reg < 4; ++reg) {
                float l = Sacc[nt][reg] * 0.125f;
                if (diag && (16 * nt + 4 * q4 + reg > irow)) l = -1e30f;  // mask sentinel
                const float e  = __expf(-fabsf(l));
                const float lb = -(fmaxf(l, 0.f) + __logf(1.f + e));     // -softplus(l)
                lv[reg] = l; lbr[reg] = lb;
            }
            const float s3 = lbr[3];
            const float s2 = lbr[2] + s3;
            const float s1 = lbr[1] + s2;
            const float s0 = lbr[0] + s1;
            ex[nt][0] = lv[0] + lbr[0] + s0;
            ex[nt][1] = lv[1] + lbr[1] + s1;
            ex[nt][2] = lv[2] + lbr[2] + s2;
            ex[nt][3] = lv[3] + lbr[3] + s3;
            sR[nt] = s0;
        }
        float gq[4], Tn[4];
        #pragma unroll
        for (int nt = 0; nt < 4; ++nt) {
            float g2 = sR[nt];
            float u = __shfl_down(g2, 16, 64); if (q4 < 3) g2 += u;
            u = __shfl_down(g2, 32, 64);       if (q4 < 2) g2 += u;
            gq[nt] = g2;                         // sum over q4' >= q4 within nt
            Tn[nt] = __shfl(g2, l16, 64);        // nt total (q4=0 lane, same i)
        }
        const float TSa[4] = { Tn[1] + Tn[2] + Tn[3], Tn[2] + Tn[3], Tn[3], 0.f };
        #pragma unroll
        for (int nt = 0; nt < 4; ++nt) {
            const float cross = (gq[nt] - sR[nt]) + TSa[nt] + Crow;
            short4v w4;
            #pragma unroll
            for (int reg = 0; reg < 4; ++reg)
                w4[reg] = bf16r(__expf(ex[nt][reg] + cross));
            *(short4v*)&Ws[irow * WPITCH + 16 * nt + 4 * q4] = w4;   // wave-local rows
        }
        Crow += TSa[0] + Tn[0];

        // ---- GEMM2: O += W V  (wa via wave-local LDS round-trip) ----
        #pragma unroll
        for (int ks = 0; ks < 2; ++ks) {
            const short8 wa = *(const short8*)&Ws[(16 * wv + l16) * WPITCH + 32 * ks + 8 * q4];
            #pragma unroll
            for (int dt = 0; dt < 4; ++dt) {
                Oacc[dt] = __builtin_amdgcn_mfma_f32_16x16x32_bf16(wa, vb[dt * 2 + ks], Oacc[dt], 0, 0, 0);
            }
        }
    }

    // ---- epilogue: C-layout scatter to partial buffer; hi also writes C ----
    #pragma unroll
    for (int dt = 0; dt < 4; ++dt)
        #pragma unroll
        for (int r = 0; r < 4; ++r)
            opart[(16 * wv + 4 * q4 + r) * 64 + 16 * dt + l16] = Oacc[dt][r];
    if (half == 0 && q4 == 0)
        Cb[(size_t)g * 64 + 16 * wv + l16] = Crow;
}

// ---------------- merge: out = O_hi + exp(C_hi) * O_lo ----------------
__global__ __launch_bounds__(256) void stickbreak_merge(
    const float* __restrict__ part, float* __restrict__ out)
{
    const int g = blockIdx.x;                 // 0..511 (= bh*16+qt)
    const int t = threadIdx.x;
    const int i = t >> 2;                     // row 0..63
    const int c0 = (t & 3) << 4;              // col base
    const float* Ohi = part + (size_t)g * 8192 + i * 64 + c0;
    const float* Olo = Ohi + 4096;
    const float e = __expf(part[(size_t)NBLOB * 8192 + (size_t)g * 64 + i]);
    float* o = out + (size_t)g * 4096 + i * 64 + c0;
    #pragma unroll
    for (int c = 0; c < 4; ++c) {
        const float4 a = ((const float4*)Ohi)[c];
        const float4 b = ((const float4*)Olo)[c];
        float4 r;
        r.x = fmaf(e, b.x, a.x);
        r.y = fmaf(e, b.y, a.y);
        r.z = fmaf(e, b.z, a.z);
        r.w = fmaf(e, b.w, a.w);
        ((float4*)o)[c] = r;
    }
}

extern "C" void kernel_launch(void* const* d_in, const int* in_sizes, int n_in,
                              void* d_out, int out_size, void* d_ws, size_t ws_size,
                              hipStream_t stream) {
    const float* q = (const float*)d_in[0];
    const float* k = (const float*)d_in[1];
    const float* v = (const float*)d_in[2];
    float* out = (float*)d_out;
    short* ws = (short*)d_ws;
    float* part = (float*)(ws + (size_t)NBLOB * BLOB_SH);   // 24.6 MB partials after 12.6 MB blobs
    stickbreak_prep<<<dim3(512), dim3(256), 0, stream>>>(k, v, ws);
    stickbreak_main<<<dim3(1024), dim3(256), 0, stream>>>(q, ws, part);
    stickbreak_merge<<<dim3(512), dim3(256), 0, stream>>>(part, out);
}